// Round 3
// baseline (109.576 us; speedup 1.0000x reference)
//
#include <hip/hip_runtime.h>
#include <stdint.h>

// Match XLA: no FMA contraction anywhere numerics feed comparisons.
#pragma clang fp contract(off)

#define B_IMG 32
#define R_N   6000
#define G_N   100
#define NS    128
#define PMAX  32
#define NBUCK 1024
#define BCAP  512
#define SEL_T 1024   // select_kernel block size (== NBUCK, one bucket/thread)
#define KPT   6      // ceil(R_N / SEL_T) register-resident items per thread

#ifndef JAX_PARTITIONABLE
#define JAX_PARTITIONABLE 1
#endif

__device__ __forceinline__ uint32_t rotl32(uint32_t v, int d) {
  return (v << d) | (v >> (32 - d));
}

// Threefry-2x32, 20 rounds, exactly as jax/_src/prng.py
__device__ __forceinline__ void tf2x32(uint32_t k0, uint32_t k1,
                                       uint32_t x0, uint32_t x1,
                                       uint32_t& o0, uint32_t& o1) {
  const uint32_t k2 = k0 ^ k1 ^ 0x1BD11BDAu;
  x0 += k0; x1 += k1;
#define TF_R(r) { x0 += x1; x1 = rotl32(x1, r); x1 ^= x0; }
  TF_R(13) TF_R(15) TF_R(26) TF_R(6)
  x0 += k1; x1 += k2 + 1u;
  TF_R(17) TF_R(29) TF_R(16) TF_R(24)
  x0 += k2; x1 += k0 + 2u;
  TF_R(13) TF_R(15) TF_R(26) TF_R(6)
  x0 += k0; x1 += k1 + 3u;
  TF_R(17) TF_R(29) TF_R(16) TF_R(24)
  x0 += k1; x1 += k2 + 4u;
  TF_R(13) TF_R(15) TF_R(26) TF_R(6)
  x0 += k2; x1 += k0 + 5u;
#undef TF_R
  o0 = x0; o1 = x1;
}

// jax.random.uniform transform for float32, minval=1e-6, maxval=1.0
__device__ __forceinline__ float tf_uniform(uint32_t bits) {
#pragma clang fp contract(off)
  float f = __uint_as_float((bits >> 9) | 0x3f800000u) - 1.0f;
  float r = f * (1.0f - 1e-6f) + 1e-6f;   // mul then add, NOT fma
  return fmaxf(1e-6f, r);
}

__device__ __forceinline__ int bucket_of(float r) {
  return min((int)(r * (float)NBUCK), NBUCK - 1);
}

// Kernel 1: per-roi r (threefry), IOU max + argmax vs 100 GTs.
__global__ __launch_bounds__(256) void prep_kernel(
    const float* __restrict__ roi, const float* __restrict__ gt,
    float* __restrict__ wr, float* __restrict__ wmiou, int* __restrict__ wgta) {
#pragma clang fp contract(off)
  const int b = blockIdx.y;
  const int i = blockIdx.x * 256 + threadIdx.x;

  __shared__ float sg[G_N * 4];
  __shared__ float sga[G_N];
  for (int t = threadIdx.x; t < G_N * 4; t += 256) sg[t] = gt[b * G_N * 4 + t];
  __syncthreads();
  if (threadIdx.x < G_N) {
    int g = threadIdx.x;
    sga[g] = (sg[g * 4 + 2] - sg[g * 4 + 0]) * (sg[g * 4 + 3] - sg[g * 4 + 1]);
  }
  __syncthreads();
  if (i >= R_N) return;

  const float4 rv = ((const float4*)roi)[(size_t)b * R_N + i];
  float x1 = rv.x, y1 = rv.y, x2 = rv.z, y2 = rv.w;
  float ar = (x2 - x1) * (y2 - y1);

  float best = -1.0f; int bi = 0;
  for (int g = 0; g < G_N; ++g) {
    float gx1 = sg[g * 4 + 0], gy1 = sg[g * 4 + 1];
    float gx2 = sg[g * 4 + 2], gy2 = sg[g * 4 + 3];
    float ix1 = fmaxf(x1, gx1), iy1 = fmaxf(y1, gy1);
    float ix2 = fminf(x2, gx2), iy2 = fminf(y2, gy2);
    float iw = fmaxf(ix2 - ix1, 0.0f);
    float ih = fmaxf(iy2 - iy1, 0.0f);
    float inter = iw * ih;
    float denom = (ar + sga[g]) - inter;
    float iou = inter / denom;
    if (iou > best) { best = iou; bi = g; }  // first-max like jnp.argmax
  }

  uint32_t bits;
#if JAX_PARTITIONABLE
  uint32_t kb0, kb1;
  tf2x32(0u, 42u, 0u, (uint32_t)b, kb0, kb1);        // foldlike split: key_b
  uint32_t t0, t1;
  tf2x32(kb0, kb1, 0u, (uint32_t)i, t0, t1);
  bits = t0 ^ t1;                                    // 32-bit partitionable bits
#else
  uint32_t kb0, kb1, d0, d1;
  if (b < 16) {
    tf2x32(0u, 42u, (uint32_t)(2 * b),     (uint32_t)(2 * b + 32), kb0, d0);
    tf2x32(0u, 42u, (uint32_t)(2 * b + 1), (uint32_t)(2 * b + 33), kb1, d1);
  } else {
    int c = b - 16;
    tf2x32(0u, 42u, (uint32_t)(2 * c),     (uint32_t)(2 * c + 32), d0, kb0);
    tf2x32(0u, 42u, (uint32_t)(2 * c + 1), (uint32_t)(2 * c + 33), d1, kb1);
  }
  uint32_t t0, t1;
  if (i < R_N / 2) { tf2x32(kb0, kb1, (uint32_t)i, (uint32_t)(i + R_N / 2), t0, t1); bits = t0; }
  else             { tf2x32(kb0, kb1, (uint32_t)(i - R_N / 2), (uint32_t)i, t0, t1); bits = t1; }
#endif

  size_t o = (size_t)b * R_N + i;
  wr[o] = tf_uniform(bits);
  wmiou[o] = best;
  wgta[o] = bi;
}

// Kernel 2: per-image selection + output write. 1 block/image, 1024 threads.
// All 6000 per-roi values live in registers (6/thread); LDS holds only the
// histogram, the boundary-bucket candidates, and the small selected lists.
__global__ __launch_bounds__(SEL_T) void select_kernel(
    const float* __restrict__ roi, const float* __restrict__ gt,
    const int* __restrict__ labels,
    const float* __restrict__ wr, const float* __restrict__ wmiou,
    const int* __restrict__ wgta, float* __restrict__ out) {
#pragma clang fp contract(off)
  const int b = blockIdx.x;
  const int tid = threadIdx.x;
  const int lane = tid & 63;
  const int wid = tid >> 6;

  __shared__ int   S[NBUCK];       // histogram -> suffix sums
  __shared__ int   wsum[16];
  __shared__ int   sh_cntpos;
  __shared__ int   sh_B, sh_A;
  __shared__ int   candIdx[BCAP];
  __shared__ float candR[BCAP];
  __shared__ int   candCnt;
  __shared__ int   posIdx[PMAX];
  __shared__ float posR[PMAX];
  __shared__ int   negIdx[NS];
  __shared__ float negR[NS];
  __shared__ int   listCnt[2];     // [0]=neg, [1]=pos
  __shared__ int   outIdx[NS];

  if (tid == 0) { sh_cntpos = 0; listCnt[0] = 0; listCnt[1] = 0; }
  if (tid < NS) outIdx[tid] = -1;

  // Register-resident load: r + class for this thread's 6 rois.
  float r[KPT];
  unsigned char cls[KPT];
  int mycnt = 0;
  for (int k = 0; k < KPT; ++k) {
    int i = tid + k * SEL_T;
    if (i < R_N) {
      r[k] = wr[(size_t)b * R_N + i];
      cls[k] = (wmiou[(size_t)b * R_N + i] >= 0.5f) ? 1 : 0;
      mycnt += cls[k];
    } else { r[k] = -1.0f; cls[k] = 255; }
  }
  for (int d = 32; d > 0; d >>= 1) mycnt += __shfl_down(mycnt, d);
  if (lane == 0 && mycnt) atomicAdd(&sh_cntpos, mycnt);
  __syncthreads();

  const int cntPos = sh_cntpos;
  const int cntNeg = R_N - cntPos;
  const int nPosSel = min(cntPos, PMAX);
  const int Kneg = NS - nPosSel;

  // Select top-quota by (r desc, idx asc) within each class.
  for (int c = 1; c >= 0; --c) {
    const int quota = (c == 1) ? PMAX : Kneg;
    const int cnt   = (c == 1) ? cntPos : cntNeg;
    int*   lidx = (c == 1) ? posIdx : negIdx;
    float* lr   = (c == 1) ? posR   : negR;
    const int cap = (c == 1) ? PMAX : NS;

    if (cnt <= quota) {
      for (int k = 0; k < KPT; ++k)
        if (cls[k] == (unsigned char)c) {
          int p = atomicAdd(&listCnt[c], 1);
          if (p < cap) { lidx[p] = tid + k * SEL_T; lr[p] = r[k]; }
        }
      __syncthreads();
      continue;
    }

    // --- histogram (one bucket per thread: SEL_T == NBUCK) ---
    S[tid] = 0;
    if (tid == 0) candCnt = 0;
    __syncthreads();
    for (int k = 0; k < KPT; ++k)
      if (cls[k] == (unsigned char)c) atomicAdd(&S[bucket_of(r[k])], 1);
    __syncthreads();

    // --- hierarchical suffix sum: S[h] = #items with bucket >= h ---
    int v = S[NBUCK - 1 - tid];
    for (int d = 1; d < 64; d <<= 1) {
      int n = __shfl_up(v, d);
      if (lane >= d) v += n;
    }
    if (lane == 63) wsum[wid] = v;
    __syncthreads();
    if (wid == 0) {
      int t = (lane < 16) ? wsum[lane] : 0;
      for (int d = 1; d < 16; d <<= 1) {
        int n = __shfl_up(t, d);
        if (lane >= d) t += n;
      }
      if (lane < 16) wsum[lane] = t;   // inclusive wave totals
    }
    __syncthreads();
    int Sval = v + ((wid > 0) ? wsum[wid - 1] : 0);
    S[NBUCK - 1 - tid] = Sval;
    __syncthreads();

    // unique boundary bucket: S[h] >= quota, S[h+1] < quota
    {
      int Sh = S[tid];
      int Sn = (tid + 1 < NBUCK) ? S[tid + 1] : 0;
      if (Sh >= quota && Sn < quota) { sh_B = tid; sh_A = Sn; }
    }
    __syncthreads();
    const int Bb = sh_B, A = sh_A;

    // --- definite winners -> list; boundary bucket -> candidates ---
    for (int k = 0; k < KPT; ++k)
      if (cls[k] == (unsigned char)c) {
        int bk = bucket_of(r[k]);
        if (bk > Bb) {
          int p = atomicAdd(&listCnt[c], 1);
          if (p < cap) { lidx[p] = tid + k * SEL_T; lr[p] = r[k]; }
        } else if (bk == Bb) {
          int p = atomicAdd(&candCnt, 1);
          if (p < BCAP) { candIdx[p] = tid + k * SEL_T; candR[p] = r[k]; }
        }
      }
    __syncthreads();

    const int M = candCnt;
    if (M <= BCAP) {
      // exact rank among the small boundary list (M ~ 6): O(M^2) parallel
      if (tid < M) {
        int i = candIdx[tid];
        float ri = candR[tid];
        int beats = 0;
        for (int u = 0; u < M; ++u) {
          int j = candIdx[u];
          float rj = candR[u];
          if (rj > ri || (rj == ri && j < i)) beats++;
        }
        if (A + beats < quota) {
          int p = atomicAdd(&listCnt[c], 1);
          if (p < cap) { lidx[p] = i; lr[p] = ri; }
        }
      }
    } else {
      // fallback (statistically never): full global rescan per own candidate
      for (int k = 0; k < KPT; ++k)
        if (cls[k] == (unsigned char)c && bucket_of(r[k]) == Bb) {
          int i = tid + k * SEL_T;
          float ri = r[k];
          int beats = 0;
          for (int j = 0; j < R_N; ++j) {
            float rj = wr[(size_t)b * R_N + j];
            unsigned char cj = (wmiou[(size_t)b * R_N + j] >= 0.5f) ? 1 : 0;
            if (cj == (unsigned char)c && bucket_of(rj) == Bb &&
                (rj > ri || (rj == ri && j < i))) beats++;
          }
          if (A + beats < quota) {
            int p = atomicAdd(&listCnt[c], 1);
            if (p < cap) { lidx[p] = i; lr[p] = ri; }
          }
        }
    }
    __syncthreads();
  }

  const int nP = min(listCnt[1], PMAX);
  const int nN = min(listCnt[0], NS);

  // Output slots: top_k on prio (2+r pos, 1+r neg), ties -> lower index first.
  // 2+r > 1+r' strictly (r' < 1), so positives occupy slots [0,nP).
  // Note: prio is the float32-rounded sum; distinct r can tie here.
  if (tid < nP) {
    int i = posIdx[tid];
    float pr = 2.0f + posR[tid];
    int slot = 0;
    for (int u = 0; u < nP; ++u) {
      int j = posIdx[u];
      float pj = 2.0f + posR[u];
      if (pj > pr || (pj == pr && j < i)) slot++;
    }
    outIdx[slot] = i;
  }
  if (tid < nN) {
    int i = negIdx[tid];
    float pr = 1.0f + negR[tid];
    int slot = 0;
    for (int u = 0; u < nN; ++u) {
      int j = negIdx[u];
      float pj = 1.0f + negR[u];
      if (pj > pr || (pj == pr && j < i)) slot++;
    }
    outIdx[nP + slot] = i;
  }
  __syncthreads();

  // Epilogue: write all three outputs (zeros for invalid filler slots).
  if (tid < NS) {
    const int p = tid;
    const int i = outIdx[p];
    float o_roi[4] = {0.f, 0.f, 0.f, 0.f};
    float o_lab = 0.f;
    float o_d[4] = {0.f, 0.f, 0.f, 0.f};
    if (i >= 0) {
      const float4 rv = ((const float4*)roi)[(size_t)b * R_N + i];
      float x1 = rv.x, y1 = rv.y, x2 = rv.z, y2 = rv.w;
      o_roi[0] = x1; o_roi[1] = y1; o_roi[2] = x2; o_roi[3] = y2;
      int g = wgta[(size_t)b * R_N + i];
      const float4 gv = ((const float4*)gt)[(size_t)b * G_N + g];
      float gx1 = gv.x, gy1 = gv.y, gx2 = gv.z, gy2 = gv.w;
      if (p < nP) o_lab = (float)labels[b * G_N + g];   // kept_pos <=> pos slot
      const float EPSF = 1.1920928955078125e-7f;  // np.finfo(f32).eps
      float w = fmaxf(x2 - x1, EPSF);
      float h = fmaxf(y2 - y1, EPSF);
      float cx = x1 + 0.5f * (x2 - x1);
      float cy = y1 + 0.5f * (y2 - y1);
      float bw = gx2 - gx1, bh = gy2 - gy1;
      float bcx = gx1 + 0.5f * bw, bcy = gy1 + 0.5f * bh;
      o_d[0] = (bcx - cx) / w;
      o_d[1] = (bcy - cy) / h;
      o_d[2] = logf(bw / w);
      o_d[3] = logf(bh / h);
    }
    float* out0 = out;                                 // [32,128,4]
    float* out1 = out + (size_t)B_IMG * NS * 4;        // [32,128]
    float* out2 = out1 + (size_t)B_IMG * NS;           // [32,128,4]
    const int base = b * NS + p;
    out0[base * 4 + 0] = o_roi[0];
    out0[base * 4 + 1] = o_roi[1];
    out0[base * 4 + 2] = o_roi[2];
    out0[base * 4 + 3] = o_roi[3];
    out1[base] = o_lab;
    out2[base * 4 + 0] = o_d[0];
    out2[base * 4 + 1] = o_d[1];
    out2[base * 4 + 2] = o_d[2];
    out2[base * 4 + 3] = o_d[3];
  }
}

extern "C" void kernel_launch(void* const* d_in, const int* in_sizes, int n_in,
                              void* d_out, int out_size, void* d_ws, size_t ws_size,
                              hipStream_t stream) {
  const float* roi    = (const float*)d_in[0];
  const float* gt     = (const float*)d_in[1];
  const int*   labels = (const int*)d_in[2];
  // d_in[3] (image) is unused by the math.

  float* wr    = (float*)d_ws;                  // [32*6000] r values
  float* wmiou = wr + (size_t)B_IMG * R_N;      // [32*6000] max IOU
  int*   wgta  = (int*)(wmiou + (size_t)B_IMG * R_N);  // [32*6000] argmax gt

  dim3 g1((R_N + 255) / 256, B_IMG);
  prep_kernel<<<g1, 256, 0, stream>>>(roi, gt, wr, wmiou, wgta);
  select_kernel<<<B_IMG, SEL_T, 0, stream>>>(roi, gt, labels, wr, wmiou, wgta,
                                             (float*)d_out);
}